// Round 7
// baseline (261.804 us; speedup 1.0000x reference)
//
#include <hip/hip_runtime.h>
#include <hip/hip_bf16.h>

// Problem constants (match reference)
#define HH 1024
#define WW 1024
#define NN (HH * WW)
#define KK 15
#define GAMMA_F 0.5f

// Block = 4 rows x 64 cols (256 threads; wave w handles row y0+w).
// Image window rows y0-4..y0+7, cols c0-4..c0+67 -> 12 x 72 tile, 10.4 KB.
#define TR 12
#define TW 72

// Async global->LDS DMA, 16B/lane, exec-masked. LDS dest must be wave-uniform;
// HW writes dest + lane*16.
__device__ __forceinline__ void cp16(const float* g, float* l) {
    __builtin_amdgcn_global_load_lds(
        (const __attribute__((address_space(1))) void*)g,
        (__attribute__((address_space(3))) void*)l, 16, 0, 0);
}

__global__ __launch_bounds__(256) void ppr_kernel(
    const float* __restrict__ s1,      // (N,)
    const float* __restrict__ s2,      // (2, N)
    const float* __restrict__ w,       // (K, N)
    const int* __restrict__ nb,        // (K, N)
    float* __restrict__ out)           // scalar
{
    __shared__ __align__(16) float t1 [TR * TW];
    __shared__ __align__(16) float t2a[TR * TW];
    __shared__ __align__(16) float t2b[TR * TW];
    __shared__ float smem[4];

    const int tid  = threadIdx.x;
    const int wv   = tid >> 6;                 // 0..3  -> pixel row within tile
    const int lane = tid & 63;                 //        -> pixel col within tile
    const int ty   = blockIdx.x >> 4;          // row band 0..255
    const int tx   = blockIdx.x & 15;          // col tile 0..15
    const int y0   = ty << 2;
    const int c0   = tx << 6;
    const int yc   = y0 + wv;
    const int xc   = c0 + lane;
    const int n    = yc * WW + xc;

    // ---- Phase 1: nb/w into VGPRs (pass-through data; element (k,n) is only
    // ever used by thread n). 30 independent coalesced loads, pinned above the
    // compute by sched_barrier below -> deep VMEM queue without LDS cost.
    int   j[KK];
    float wk[KK];
#pragma unroll
    for (int k = 0; k < KK; ++k) j[k]  = nb[(size_t)k * NN + n];
#pragma unroll
    for (int k = 0; k < KK; ++k) wk[k] = w[(size_t)k * NN + n];

    // ---- Phase 2: DMA the 12x72 image window (3 arrays x 12 rows = 36 ops,
    // 9 per wave, 17-18 active lanes each). Edge tiles shift the source start
    // instead of clamping; skipped LDS cells are never read (clamped coords).
    int xs = c0 - 4, dof = 0, nl = 18;         // src col start, dest offset, lanes
    if (tx == 0)       { xs = 0; dof = 4; nl = 17; }
    else if (tx == 15) { nl = 17; }

    for (int t = wv; t < 36; t += 4) {
        const int arr = t / 12;                // 0:s1 1:s2a 2:s2b
        const int rr  = t - arr * 12;          // tile row 0..11
        int gy = y0 - 4 + rr;
        gy = gy < 0 ? 0 : (gy > HH - 1 ? HH - 1 : gy);
        const float* src =
            (arr == 0 ? s1 : (arr == 1 ? s2 : s2 + NN)) + (size_t)gy * WW + xs;
        float* dst =
            (arr == 0 ? t1 : (arr == 1 ? t2a : t2b)) + rr * TW + dof;
        if (lane < nl) cp16(src + lane * 4, dst);
    }

    __builtin_amdgcn_sched_barrier(0);  // nothing crosses: loads stay issued
    __syncthreads();                    // vmcnt(0) drain: DMA + VGPR loads done

    // Own-pixel values from the tile center.
    const int own = (wv + 4) * TW + lane + 4;
    const float s1n = t1[own];
    const float s2a = t2a[own];
    const float s2b = t2b[own];

    // LDS offset for neighbor (yn,xn): (yn-y0+4)*TW + (xn-c0+4)
    const int cbase = (4 - y0) * TW + 4 - c0;

    float acc1 = 0.0f, acc2 = 0.0f;
#pragma unroll
    for (int k = 0; k < KK; ++k) {
        const int jj = j[k];
        const int yn = jj >> 10;
        const int xn = jj & (WW - 1);
        const int off = yn * TW + xn + cbase;
        const float g1  = t1[off];
        const float g2a = t2a[off];
        const float g2b = t2b[off];

        const float d0 = (float)(xc - xn);     // == dist[k,0,n] exactly
        const float d1 = (float)(yc - yn);     // == dist[k,1,n] exactly

        const float plane = fmaf(s2a, d0, s2b * d1);
        const float a1 = (s1n - g1 - plane) * wk[k];
        acc1 = fmaf(a1, a1, acc1);

        const float e0 = s2a - g2a;
        const float e1 = s2b - g2b;
        acc2 = fmaf(sqrtf(fmaf(e0, e0, e1 * e1)), wk[k], acc2);
    }
    float local = sqrtf(acc1) + GAMMA_F * acc2;

    // ---- Wave (64-lane) then block reduction, one atomic per block.
#pragma unroll
    for (int off2 = 32; off2 > 0; off2 >>= 1)
        local += __shfl_down(local, off2, 64);

    if (lane == 0) smem[wv] = local;
    __syncthreads();

    if (tid == 0) {
        const float s = smem[0] + smem[1] + smem[2] + smem[3];
        atomicAdd(out, s * (1.0f / (float)NN));  // MULTIPLIER == 1.0
    }
}

extern "C" void kernel_launch(void* const* d_in, const int* in_sizes, int n_in,
                              void* d_out, int out_size, void* d_ws, size_t ws_size,
                              hipStream_t stream) {
    const float* s1   = (const float*)d_in[0];  // sig1 (1,1,H,W)
    const float* s2   = (const float*)d_in[1];  // sig2 (1,2,H,W)
    const float* w    = (const float*)d_in[2];  // weights (K,N)
    // d_in[3] (dist) unused: derived exactly from neighbours.
    const int*   nb   = (const int*)d_in[4];    // neighbours (K,N)
    float* out = (float*)d_out;

    // d_out is re-poisoned to 0xAA before every timed launch; zero it first.
    hipMemsetAsync(out, 0, sizeof(float) * (size_t)out_size, stream);

    const int block = 256;
    const int grid  = NN / block;   // 4096 blocks, exact
    ppr_kernel<<<grid, block, 0, stream>>>(s1, s2, w, nb, out);
}

// Round 8
// 248.001 us; speedup vs baseline: 1.0557x; 1.0557x over previous
//
#include <hip/hip_runtime.h>
#include <hip/hip_bf16.h>

// Problem constants (match reference)
#define HH 1024
#define WW 1024
#define NN (HH * WW)
#define KK 15
#define GAMMA_F 0.5f

// Block = 4 rows x 128 cols (256 threads, 2 adjacent cols per thread).
// Image window rows y0-4..y0+7, cols c0-4..c0+131 -> 12 x 136 tile, 19.6 KB.
#define TR 12
#define TW 136

// Async global->LDS DMA, 16B/lane, exec-masked; HW writes dest + lane*16.
__device__ __forceinline__ void cp16(const float* g, float* l) {
    __builtin_amdgcn_global_load_lds(
        (const __attribute__((address_space(1))) void*)g,
        (__attribute__((address_space(3))) void*)l, 16, 0, 0);
}

__global__ __launch_bounds__(256) void ppr_kernel(
    const float* __restrict__ s1,      // (N,)
    const float* __restrict__ s2,      // (2, N)
    const float* __restrict__ w,       // (K, N)
    const int* __restrict__ nb,        // (K, N)
    float* __restrict__ out)           // scalar
{
    __shared__ __align__(16) float t1 [TR * TW];
    __shared__ __align__(16) float t2a[TR * TW];
    __shared__ __align__(16) float t2b[TR * TW];
    __shared__ float smem[4];

    const int tid  = threadIdx.x;
    const int wv   = tid >> 6;                 // 0..3 -> pixel row within tile
    const int lane = tid & 63;
    const int ty   = blockIdx.x >> 3;          // row band 0..255
    const int tx   = blockIdx.x & 7;           // col tile 0..7
    const int y0   = ty << 2;
    const int c0   = tx << 7;
    const int yc   = y0 + wv;
    const int xc0  = c0 + (lane << 1);         // this thread's 2 cols
    const int n    = yc * WW + xc0;            // even -> 8B aligned

    // ---- Phase 1: nb/w pairs into VGPRs (pass-through data). 30 dwordx2
    // loads, all independent, pinned above compute by sched_barrier below.
    int2   j2[KK];
    float2 w2[KK];
#pragma unroll
    for (int k = 0; k < KK; ++k) j2[k] = *(const int2*)(nb + (size_t)k * NN + n);
#pragma unroll
    for (int k = 0; k < KK; ++k) w2[k] = *(const float2*)(w + (size_t)k * NN + n);

    // ---- Phase 2: DMA the 12x136 window (3 arrays x 12 rows = 36 ops,
    // 9 per wave, 33-34 active lanes). Edge tiles shift the source start;
    // skipped LDS cells correspond to clamped-away coords, never read.
    int xs = c0 - 4, dof = 0, nl = 34;
    if (tx == 0)      { xs = 0; dof = 4; nl = 33; }
    else if (tx == 7) { nl = 33; }

#pragma unroll
    for (int it = 0; it < 9; ++it) {
        const int t   = wv * 9 + it;           // 0..35, wave-uniform
        const int arr = t / 12;                // 0:s1 1:s2a 2:s2b (scalar div)
        const int rr  = t - arr * 12;          // tile row 0..11
        int gy = y0 - 4 + rr;
        gy = gy < 0 ? 0 : (gy > HH - 1 ? HH - 1 : gy);
        const float* src =
            (arr == 0 ? s1 : (arr == 1 ? s2 : s2 + NN)) + (size_t)gy * WW + xs;
        float* dst = (arr == 0 ? t1 : (arr == 1 ? t2a : t2b)) + rr * TW + dof;
        if (lane < nl) cp16(src + lane * 4, dst);
    }

    __builtin_amdgcn_sched_barrier(0);  // keep all loads issued up-front
    __syncthreads();                    // vmcnt(0): DMA + VGPR loads complete

    // Own-pixel values from the tile center row.
    const int own0 = (wv + 4) * TW + (lane << 1) + 4;
    const float s1n_0 = t1 [own0],     s1n_1 = t1 [own0 + 1];
    const float s2a_0 = t2a[own0],     s2a_1 = t2a[own0 + 1];
    const float s2b_0 = t2b[own0],     s2b_1 = t2b[own0 + 1];

    // LDS offset for neighbor (yn,xn): (yn-y0+4)*TW + (xn-c0+4)
    const int cbase = (4 - y0) * TW + 4 - c0;

    float acc1_0 = 0.f, acc2_0 = 0.f, acc1_1 = 0.f, acc2_1 = 0.f;
#pragma unroll
    for (int k = 0; k < KK; ++k) {
        // pixel 0
        {
            const int jj = j2[k].x;
            const int yn = jj >> 10;
            const int xn = jj & (WW - 1);
            const int off = yn * TW + xn + cbase;
            const float g1  = t1 [off];
            const float g2a = t2a[off];
            const float g2b = t2b[off];
            const float d0 = (float)(xc0 - xn);
            const float d1 = (float)(yc  - yn);
            const float wkk = w2[k].x;
            const float plane = fmaf(s2a_0, d0, s2b_0 * d1);
            const float a1 = (s1n_0 - g1 - plane) * wkk;
            acc1_0 = fmaf(a1, a1, acc1_0);
            const float e0 = s2a_0 - g2a;
            const float e1 = s2b_0 - g2b;
            acc2_0 = fmaf(sqrtf(fmaf(e0, e0, e1 * e1)), wkk, acc2_0);
        }
        // pixel 1
        {
            const int jj = j2[k].y;
            const int yn = jj >> 10;
            const int xn = jj & (WW - 1);
            const int off = yn * TW + xn + cbase;
            const float g1  = t1 [off];
            const float g2a = t2a[off];
            const float g2b = t2b[off];
            const float d0 = (float)(xc0 + 1 - xn);
            const float d1 = (float)(yc - yn);
            const float wkk = w2[k].y;
            const float plane = fmaf(s2a_1, d0, s2b_1 * d1);
            const float a1 = (s1n_1 - g1 - plane) * wkk;
            acc1_1 = fmaf(a1, a1, acc1_1);
            const float e0 = s2a_1 - g2a;
            const float e1 = s2b_1 - g2b;
            acc2_1 = fmaf(sqrtf(fmaf(e0, e0, e1 * e1)), wkk, acc2_1);
        }
    }
    float local = sqrtf(acc1_0) + sqrtf(acc1_1)
                + GAMMA_F * (acc2_0 + acc2_1);

    // ---- Wave (64-lane) then block reduction, one atomic per block.
#pragma unroll
    for (int off2 = 32; off2 > 0; off2 >>= 1)
        local += __shfl_down(local, off2, 64);

    if (lane == 0) smem[wv] = local;
    __syncthreads();

    if (tid == 0) {
        const float s = smem[0] + smem[1] + smem[2] + smem[3];
        atomicAdd(out, s * (1.0f / (float)NN));  // MULTIPLIER == 1.0
    }
}

extern "C" void kernel_launch(void* const* d_in, const int* in_sizes, int n_in,
                              void* d_out, int out_size, void* d_ws, size_t ws_size,
                              hipStream_t stream) {
    const float* s1   = (const float*)d_in[0];  // sig1 (1,1,H,W)
    const float* s2   = (const float*)d_in[1];  // sig2 (1,2,H,W)
    const float* w    = (const float*)d_in[2];  // weights (K,N)
    // d_in[3] (dist) unused: derived exactly from neighbours.
    const int*   nb   = (const int*)d_in[4];    // neighbours (K,N)
    float* out = (float*)d_out;

    // d_out is re-poisoned to 0xAA before every timed launch; zero it first.
    hipMemsetAsync(out, 0, sizeof(float) * (size_t)out_size, stream);

    const int block = 256;
    const int grid  = NN / (block * 2);   // 2048 blocks, exact
    ppr_kernel<<<grid, block, 0, stream>>>(s1, s2, w, nb, out);
}